// Round 11
// baseline (455.366 us; speedup 1.0000x reference)
//
#include <hip/hip_runtime.h>
#include <hip/hip_bf16.h>
#include <stdint.h>

// DecoderCell, folded algebra + bf16-MFMA flash attention (v7: inline kB tail).
//   k0: per b: q1 = graph@Wqf + ctx@Wqs; wq packed as bf16 MFMA A-frags; cnt[b]=0
//   kA: per (b, PAIR of 64-row slices): stage -> bf16 LDS, scores^T via
//       mfma_16x16x32_bf16, softmax, P@node via MFMA (verified scalar-gather)
//       -> bf16 partials + (m,z). LAST block per b (device atomic) runs the
//       combine inline: wt-weighted s -> mha -> q2 -> w2  (LDS overlay on tA).
//   k5: logits: mask ? -1e9 : 10*tanh(node[n,:].w2)   (streaming, 4096 blocks)

#define DD 128
#define NH 8
#define DHD 16
#define NS 16
#define TILE 64
#define RP 132
#define NMAX_PAD 1024

typedef short v8s __attribute__((ext_vector_type(8)));
typedef float v4f __attribute__((ext_vector_type(4)));

__device__ __forceinline__ unsigned short f2bf(float x) {
    unsigned u = __float_as_uint(x);
    u += 0x7fffu + ((u >> 16) & 1u);   // RNE
    return (unsigned short)(u >> 16);
}
__device__ __forceinline__ float bf2f(unsigned short s) {
    return __uint_as_float((unsigned)s << 16);
}
__device__ __forceinline__ unsigned packbf2(float x, float y) {
    union { __hip_bfloat162 h; unsigned u; } cvt;
    cvt.h = __float22bfloat162_rn(make_float2(x, y));  // v_cvt_pk_bf16_f32
    return cvt.u;
}

__device__ __forceinline__ bool detect_mask32(const void* maskp) {
    // int32 0/1 mask -> first 16 words all <=1; packed bool8 -> P ~ 3e-15
    const uint32_t* mw = (const uint32_t*)maskp;
    bool m32 = true;
    #pragma unroll
    for (int i = 0; i < 16; ++i) m32 = m32 && (mw[i] <= 1u);
    return m32;
}

// ---------------- k0: folded query -> packed bf16 A-fragments (+cnt reset) ----------------
__global__ __launch_bounds__(128)
void k0_prep(const float* __restrict__ graph, const float* __restrict__ ctx,
             const float* __restrict__ Wk1, const float* __restrict__ Wqf,
             const float* __restrict__ Wqs, unsigned short* __restrict__ wq_frag,
             int* __restrict__ cnt)
{
    __shared__ float q1[DD];
    __shared__ float wql[NH][DD];
    const int b = blockIdx.x, tid = threadIdx.x;
    if (tid == 0) cnt[b] = 0;                    // barrier counter reset (graph-safe)
    const float* ge = graph + (size_t)b * DD;
    const float* sc = ctx + (size_t)b * (DD + 2);
    float acc = 0.f;
    #pragma unroll 4
    for (int k = 0; k < DD; ++k)     acc += ge[k] * Wqf[k * DD + tid];
    #pragma unroll 4
    for (int k = 0; k < DD + 2; ++k) acc += sc[k] * Wqs[k * DD + tid];
    q1[tid] = acc;
    __syncthreads();
    {
        const float* wrow = Wk1 + (size_t)tid * DD;   // row dp = tid
        #pragma unroll
        for (int h = 0; h < NH; ++h) {
            float a = 0.f;
            #pragma unroll
            for (int j = 0; j < DHD; ++j) a += wrow[h * DHD + j] * q1[h * DHD + j];
            wql[h][tid] = 0.25f * a;   // 1/sqrt(16)
        }
    }
    __syncthreads();
    // wq_frag[(b*64+l)*32 + kk*8 + i] = bf16(wql[c][kk*32+g*8+i]), c=l&15, g=l>>4
    for (int idx = tid; idx < 64 * 4; idx += 128) {
        const int l = idx >> 2, kk = idx & 3;
        const int c = l & 15, g = l >> 4;
        unsigned short v[8];
        if (c < NH) {
            #pragma unroll
            for (int i = 0; i < 8; ++i) v[i] = f2bf(wql[c][kk * 32 + g * 8 + i]);
        } else {
            #pragma unroll
            for (int i = 0; i < 8; ++i) v[i] = 0;
        }
        *(v8s*)&wq_frag[((size_t)b * 64 + l) * 32 + kk * 8] = *(v8s*)v;
    }
}

// ---------------- kA: MFMA flash over TWO slices + inline combine tail ----------------
// mfma_f32_16x16x32_bf16 lane layout (c=lane&15, g=lane>>4):
//   A[m][k]: m=c, k=g*8+i   B[k][n]: k=g*8+i, n=c   C[m][n]: m=g*4+r, n=c
__global__ __launch_bounds__(256)
void kA_mfma(const float* __restrict__ node, const unsigned short* __restrict__ wq_frag,
             const void* __restrict__ maskp, unsigned short* __restrict__ spart_ws,
             float* __restrict__ mz_ws, float* __restrict__ w2_ws,
             const float* __restrict__ Wv, const float* __restrict__ Wout,
             const float* __restrict__ Wk2, int* __restrict__ cnt, int N)
{
    __shared__ __align__(16) unsigned short tA[8][TILE][16]; // 16 KB node tile (bf16, col-subtiled)
    __shared__ __align__(16) unsigned short Ph[16][72];      // P^T [head][row]
    __shared__ float wmax[16][5];
    __shared__ float zpart[16][5];
    __shared__ int lastflag;

    const int b = blockIdx.y, jj = blockIdx.x, tid = threadIdx.x;
    const int lane = tid & 63, w = tid >> 6;     // 4 waves
    const int c = lane & 15, g = lane >> 4;
    const int rows = (N + NS - 1) / NS;
    const int j0 = 2 * jj;

    const float* nodeB = node + (size_t)b * N * DD;
    const bool m32 = detect_mask32(maskp);
    const int32_t* mi = (const int32_t*)maskp + (size_t)b * N;
    const uint8_t* mb = (const uint8_t*)maskp + (size_t)b * N;

    // staging geometry: consecutive tids read consecutive 16B
    const int srow = tid >> 5;           // 0..7
    const int scol = (tid & 31) * 4;     // 0..124
    const int sch = scol >> 4, sc0 = scol & 15;

    auto load_slice = [&](int n0, int nend, float4* f) {
        const int nrows = nend - n0;
        #pragma unroll
        for (int i = 0; i < 8; ++i) {
            const int r = i * 8 + srow;
            f[i] = make_float4(0.f, 0.f, 0.f, 0.f);
            if (r < nrows)
                f[i] = *(const float4*)(nodeB + (size_t)(n0 + r) * DD + scol);
        }
    };
    auto store_slice = [&](const float4* f) {
        #pragma unroll
        for (int i = 0; i < 8; ++i) {
            const int r = i * 8 + srow;
            unsigned d[2];
            d[0] = packbf2(f[i].x, f[i].y);
            d[1] = packbf2(f[i].z, f[i].w);
            *(unsigned long long*)&tA[sch][r][sc0] = *(unsigned long long*)d;
        }
    };
    auto empty_slice = [&](int j) {
        unsigned short* sp = spart_ws + ((size_t)b * NS + j) * NH * DD;
        for (int o = tid; o < NH * DD; o += 256) sp[o] = 0;
        if (tid < NH) {
            float* mzp = mz_ws + (((size_t)b * NS + j) * NH + tid) * 2;
            mzp[0] = -1e30f; mzp[1] = 0.f;
        }
    };

    auto compute_slice = [&](int j, int n0, int nend, const v8s* aw) {
        const int nrow = n0 + w * 16 + c;
        v4f sc = {0.f, 0.f, 0.f, 0.f};
        #pragma unroll
        for (int kk = 0; kk < 4; ++kk) {
            const v8s bfrag = *(const v8s*)&tA[2 * kk + (g >> 1)][w * 16 + c][(g & 1) * 8];
            sc = __builtin_amdgcn_mfma_f32_16x16x32_bf16(aw[kk], bfrag, sc, 0, 0, 0);
        }
        float s4[4];
        {
            const bool valid = nrow < nend;
            const bool msk = valid && (m32 ? (mi[nrow] != 0) : (mb[nrow] != 0));
            #pragma unroll
            for (int r = 0; r < 4; ++r)
                s4[r] = !valid ? -1e30f : (msk ? -1e9f : sc[r]);
        }
        {
            float mx[4];
            #pragma unroll
            for (int r = 0; r < 4; ++r) mx[r] = s4[r];
            #pragma unroll
            for (int d = 1; d < 16; d <<= 1) {
                #pragma unroll
                for (int r = 0; r < 4; ++r) mx[r] = fmaxf(mx[r], __shfl_xor(mx[r], d));
            }
            if (c == 0) {
                #pragma unroll
                for (int r = 0; r < 4; ++r) wmax[g * 4 + r][w] = mx[r];
            }
        }
        __syncthreads();
        {
            float e4[4];
            #pragma unroll
            for (int r = 0; r < 4; ++r) {
                const int h = g * 4 + r;
                const float m = fmaxf(fmaxf(wmax[h][0], wmax[h][1]),
                                      fmaxf(wmax[h][2], wmax[h][3]));
                e4[r] = __expf(s4[r] - m);
            }
            float zr[4];
            #pragma unroll
            for (int r = 0; r < 4; ++r) zr[r] = e4[r];
            #pragma unroll
            for (int d = 1; d < 16; d <<= 1) {
                #pragma unroll
                for (int r = 0; r < 4; ++r) zr[r] += __shfl_xor(zr[r], d);
            }
            if (c == 0) {
                #pragma unroll
                for (int r = 0; r < 4; ++r) zpart[g * 4 + r][w] = zr[r];
            }
            #pragma unroll
            for (int r = 0; r < 4; ++r)
                Ph[g * 4 + r][w * 16 + c] = f2bf(e4[r]);
        }
        __syncthreads();
        v4f c0v = {0.f, 0.f, 0.f, 0.f}, c1v = {0.f, 0.f, 0.f, 0.f};
        #pragma unroll
        for (int sl = 0; sl < 2; ++sl) {
            const v8s pa = *(const v8s*)&Ph[c][sl * 32 + g * 8];
            v8s bb0, bb1;
            #pragma unroll
            for (int i = 0; i < 8; ++i) {
                const int kr = sl * 32 + g * 8 + i;
                bb0[i] = (short)tA[2 * w][kr][c];
                bb1[i] = (short)tA[2 * w + 1][kr][c];
            }
            c0v = __builtin_amdgcn_mfma_f32_16x16x32_bf16(pa, bb0, c0v, 0, 0, 0);
            c1v = __builtin_amdgcn_mfma_f32_16x16x32_bf16(pa, bb1, c1v, 0, 0, 0);
        }
        if (g < 2) {
            unsigned short* sp = spart_ws + ((size_t)b * NS + j) * NH * DD;
            #pragma unroll
            for (int r = 0; r < 4; ++r) {
                sp[(g * 4 + r) * DD + (2 * w)     * 16 + c] = f2bf(c0v[r]);
                sp[(g * 4 + r) * DD + (2 * w + 1) * 16 + c] = f2bf(c1v[r]);
            }
        }
        if (tid < NH) {
            const float z = zpart[tid][0] + zpart[tid][1] + zpart[tid][2] + zpart[tid][3];
            const float m = fmaxf(fmaxf(wmax[tid][0], wmax[tid][1]),
                                  fmaxf(wmax[tid][2], wmax[tid][3]));
            float* mzp = mz_ws + (((size_t)b * NS + j) * NH + tid) * 2;
            mzp[0] = m;
            mzp[1] = z;
        }
    };

    const int n0_a = j0 * rows,       nend_a = min(n0_a + rows, N);
    const int n0_b = (j0 + 1) * rows, nend_b = min(n0_b + rows, N);
    const bool have_a = n0_a < nend_a;
    const bool have_b = n0_b < nend_b;

    if (have_a) {
        v8s aw[4];
        {
            const unsigned short* wf = wq_frag + ((size_t)b * 64 + lane) * 32;
            #pragma unroll
            for (int kk = 0; kk < 4; ++kk)
                aw[kk] = *(const v8s*)&wf[kk * 8];
        }
        float4 fr[8];
        load_slice(n0_a, nend_a, fr);
        store_slice(fr);
        float4 fr2[8];
        if (have_b) load_slice(n0_b, nend_b, fr2);   // issue early; lands during compute A
        __syncthreads();              // tile A ready
        compute_slice(j0, n0_a, nend_a, aw);
        __syncthreads();              // all PV reads of tA done
        if (have_b) {
            store_slice(fr2);
            __syncthreads();          // tile B ready
            compute_slice(j0 + 1, n0_b, nend_b, aw);
        } else if (j0 + 1 < NS) {
            empty_slice(j0 + 1);
        }
    } else {
        empty_slice(j0);
        __syncthreads();
        if (j0 + 1 < NS) empty_slice(j0 + 1);
    }

    // ---- arrive: device-scope release of this block's spart/mz writes
    __threadfence();
    __syncthreads();
    if (tid == 0) lastflag = (atomicAdd(&cnt[b], 1) == gridDim.x - 1) ? 1 : 0;
    __syncthreads();
    if (!lastflag) return;

    // ======== inline kB (last block of this b only; tA region is dead -> overlay) ========
    __threadfence();   // acquire: make other blocks' spart/mz writes visible
    float* m_l   = (float*)&tA[0][0][0];   // 128
    float* z_l   = m_l + NH * NS;          // 128
    float* wt    = z_l + NH * NS;          // 128
    float* s_l   = wt + NH * NS;           // 1024
    float* mha_l = s_l + NH * DD;          // 128
    float* q2_l  = mha_l + DD;             // 128   (total 6656 B < 16 KB)
    __syncthreads();   // tA reads above done before overlay writes (redundant but safe)

    if (tid < NH * NS) {
        const int h = tid >> 4, js = tid & 15;
        const float* mzp = mz_ws + (((size_t)b * NS + js) * NH + h) * 2;
        m_l[h * NS + js] = mzp[0];
        z_l[h * NS + js] = mzp[1];
    }
    __syncthreads();
    if (tid < NH) {
        const int h = tid;
        float M = -1e30f;
        #pragma unroll
        for (int js = 0; js < NS; ++js) M = fmaxf(M, m_l[h * NS + js]);
        float Z = 0.f;
        float wv[NS];
        #pragma unroll
        for (int js = 0; js < NS; ++js) {
            wv[js] = __expf(m_l[h * NS + js] - M);
            Z += z_l[h * NS + js] * wv[js];
        }
        const float rz = 1.f / Z;
        #pragma unroll
        for (int js = 0; js < NS; ++js) wt[h * NS + js] = wv[js] * rz;
    }
    __syncthreads();
    {
        const unsigned short* sp = spart_ws + (size_t)b * NS * NH * DD;
        for (int o = tid; o < NH * DD; o += 256) {
            const int h = o >> 7;
            float s = 0.f;
            #pragma unroll
            for (int js = 0; js < NS; ++js)
                s += bf2f(sp[(size_t)js * NH * DD + o]) * wt[h * NS + js];
            s_l[o] = s;
        }
    }
    __syncthreads();
    if (tid < DD) {   // mha[e] = s[h(e)] . Wv[:,e]
        const int h = tid >> 4;
        float a = 0.f;
        for (int dp = 0; dp < DD; ++dp) a += s_l[h * DD + dp] * Wv[dp * DD + tid];
        mha_l[tid] = a;
    }
    __syncthreads();
    if (tid < DD) {   // q2 = mha @ Wout
        float a = 0.f;
        for (int e = 0; e < DD; ++e) a += mha_l[e] * Wout[e * DD + tid];
        q2_l[tid] = a;
    }
    __syncthreads();
    if (tid < DD) {   // w2 = (Wk2 @ q2) / sqrt(128)
        const float4* row = (const float4*)(Wk2 + (size_t)tid * DD);
        float a = 0.f;
        #pragma unroll
        for (int k = 0; k < 32; ++k) {
            const float4 wv = row[k];
            a += wv.x * q2_l[4*k] + wv.y * q2_l[4*k+1] + wv.z * q2_l[4*k+2] + wv.w * q2_l[4*k+3];
        }
        w2_ws[(size_t)b * DD + tid] = a * 0.08838834764831845f;  // 1/sqrt(128)
    }
}

// ---------------- k5: logits ----------------
__global__ __launch_bounds__(256)
void k5_logits(const float* __restrict__ node, const float* __restrict__ w2_ws,
               const void* __restrict__ maskp, float* __restrict__ out, int N)
{
    const int b = blockIdx.y, j = blockIdx.x, tid = threadIdx.x;
    const int rows = (N + NS - 1) / NS;
    const int n0 = j * rows;
    const int nend = min(n0 + rows, N);
    const bool m32 = detect_mask32(maskp);
    const int32_t* mi = (const int32_t*)maskp + (size_t)b * N;
    const uint8_t* mb = (const uint8_t*)maskp + (size_t)b * N;
    const int sub = tid & 7, rr = tid >> 3;

    const float4* wv = (const float4*)(w2_ws + (size_t)b * DD + sub * 16);
    const float4 w0 = wv[0], w1 = wv[1], w2v = wv[2], w3 = wv[3];
    const float* nodeB = node + (size_t)b * N * DD;
    float* outB = out + (size_t)b * N;

    for (int n = n0 + rr; n < nend; n += 32) {
        const float4* nr = (const float4*)(nodeB + (size_t)n * DD + sub * 16);
        const float4 a0 = nr[0], a1 = nr[1], a2 = nr[2], a3 = nr[3];
        float p = a0.x*w0.x + a0.y*w0.y + a0.z*w0.z + a0.w*w0.w
                + a1.x*w1.x + a1.y*w1.y + a1.z*w1.z + a1.w*w1.w
                + a2.x*w2v.x + a2.y*w2v.y + a2.z*w2v.z + a2.w*w2v.w
                + a3.x*w3.x + a3.y*w3.y + a3.z*w3.z + a3.w*w3.w;
        p += __shfl_xor(p, 1);
        p += __shfl_xor(p, 2);
        p += __shfl_xor(p, 4);
        if (sub == 0) {
            const bool m = m32 ? (mi[n] != 0) : (mb[n] != 0);
            const float t = 1.f - 2.f / (__expf(2.f * p) + 1.f);  // tanh
            outB[n] = m ? -1e9f : 10.f * t;
        }
    }
}

// ================ fallback: round-1 monolithic kernel ================
#define TPB 512
#define NMAX 1000
#define SPAD 9

__global__ __launch_bounds__(TPB)
void decoder_fallback(const float* __restrict__ node, const float* __restrict__ graph,
                      const float* __restrict__ ctx, const void* __restrict__ maskp,
                      const float* __restrict__ Wk1, const float* __restrict__ Wv,
                      const float* __restrict__ Wk2, const float* __restrict__ Wqf,
                      const float* __restrict__ Wout, const float* __restrict__ Wqs,
                      float* __restrict__ out, int N)
{
    __shared__ float node_tile[TILE * RP];
    __shared__ float scores[NMAX * SPAD];
    __shared__ float wq[NH * RP];
    __shared__ float s_lds[NH * RP];
    __shared__ float q1[DD];
    __shared__ float mha[DD];
    __shared__ float q2[DD];
    __shared__ float w2[DD];

    const int b = blockIdx.x, tid = threadIdx.x, lane = tid & 63, wave = tid >> 6;
    const bool mask32 = detect_mask32(maskp);
    const int32_t* mi = (const int32_t*)maskp + (size_t)b * N;
    const uint8_t* mb = (const uint8_t*)maskp + (size_t)b * N;
    const float* nodeB = node + (size_t)b * N * DD;

    if (tid < DD) {
        const float* ge = graph + (size_t)b * DD;
        const float* sc = ctx + (size_t)b * (DD + 2);
        float acc = 0.f;
        for (int k = 0; k < DD; ++k)     acc += ge[k] * Wqf[k * DD + tid];
        for (int k = 0; k < DD + 2; ++k) acc += sc[k] * Wqs[k * DD + tid];
        q1[tid] = acc;
    }
    __syncthreads();
    for (int idx = tid; idx < NH * DD; idx += TPB) {
        const int h = idx >> 7, dp = idx & (DD - 1);
        const float* wrow = Wk1 + dp * DD + h * DHD;
        float acc = 0.f;
        #pragma unroll
        for (int j = 0; j < DHD; ++j) acc += wrow[j] * q1[h * DHD + j];
        wq[h * RP + dp] = 0.25f * acc;
    }
    __syncthreads();
    const int ntiles = (N + TILE - 1) / TILE;
    const int n_local = tid >> 3, hA = tid & 7;
    for (int t = 0; t < ntiles; ++t) {
        const int n0 = t * TILE;
        #pragma unroll
        for (int cc = 0; cc < 4; ++cc) {
            const int idx = cc * (TPB * 4) + tid * 4;
            const int row = idx >> 7, col = idx & (DD - 1);
            if (n0 + row < N)
                *(float4*)&node_tile[row * RP + col] =
                    *(const float4*)(nodeB + (size_t)(n0 + row) * DD + col);
        }
        __syncthreads();
        if (n0 + n_local < N) {
            const float4* nr = (const float4*)&node_tile[n_local * RP];
            const float4* wr = (const float4*)&wq[hA * RP];
            float acc = 0.f;
            #pragma unroll
            for (int k = 0; k < DD / 4; ++k) {
                const float4 a = nr[k], wv = wr[k];
                acc += a.x * wv.x + a.y * wv.y + a.z * wv.z + a.w * wv.w;
            }
            scores[(n0 + n_local) * SPAD + hA] = acc;
        }
        __syncthreads();
    }
    {
        const int h = wave;
        float sm[16];
        #pragma unroll
        for (int k = 0; k < 16; ++k) {
            const int n = lane + 64 * k;
            float v = -1e9f;
            if (n < N) {
                const bool m = mask32 ? (mi[n] != 0) : (mb[n] != 0);
                v = m ? -1e9f : scores[n * SPAD + h];
            }
            sm[k] = v;
        }
        float mx = sm[0];
        #pragma unroll
        for (int k = 1; k < 16; ++k) mx = fmaxf(mx, sm[k]);
        #pragma unroll
        for (int d = 1; d < 64; d <<= 1) mx = fmaxf(mx, __shfl_xor(mx, d));
        float e[16];
        float sum = 0.f;
        #pragma unroll
        for (int k = 0; k < 16; ++k) {
            const int n = lane + 64 * k;
            e[k] = (n < N) ? __expf(sm[k] - mx) : 0.f;
            sum += e[k];
        }
        #pragma unroll
        for (int d = 1; d < 64; d <<= 1) sum += __shfl_xor(sum, d);
        const float rinv = 1.f / sum;
        #pragma unroll
        for (int k = 0; k < 16; ++k) {
            const int n = lane + 64 * k;
            if (n < N) scores[n * SPAD + h] = e[k] * rinv;
        }
    }
    __syncthreads();
    {
        const int h = wave;
        const float2* n2 = (const float2*)nodeB;
        float a0 = 0.f, a1 = 0.f;
        #pragma unroll 4
        for (int n = 0; n < N; ++n) {
            const float at = scores[n * SPAD + h];
            const float2 v = n2[(size_t)n * 64 + lane];
            a0 += at * v.x;
            a1 += at * v.y;
        }
        s_lds[h * RP + 2 * lane] = a0;
        s_lds[h * RP + 2 * lane + 1] = a1;
    }
    __syncthreads();
    if (tid < DD) {
        const int h = tid >> 4;
        float acc = 0.f;
        for (int dp = 0; dp < DD; ++dp) acc += s_lds[h * RP + dp] * Wv[dp * DD + tid];
        mha[tid] = acc;
    }
    __syncthreads();
    if (tid < DD) {
        float acc = 0.f;
        for (int e = 0; e < DD; ++e) acc += mha[e] * Wout[e * DD + tid];
        q2[tid] = acc;
    }
    __syncthreads();
    if (tid < DD) {
        const float4* row = (const float4*)(Wk2 + tid * DD);
        float acc = 0.f;
        #pragma unroll
        for (int k = 0; k < DD / 4; ++k) {
            const float4 wv = row[k];
            acc += wv.x * q2[4*k] + wv.y * q2[4*k+1] + wv.z * q2[4*k+2] + wv.w * q2[4*k+3];
        }
        w2[tid] = acc * 0.08838834764831845f;
    }
    __syncthreads();
    {
        const float wa = w2[2 * lane], wb = w2[2 * lane + 1];
        const float2* n2 = (const float2*)nodeB;
        float* outB = out + (size_t)b * N;
        for (int n = wave; n < N; n += NH) {
            const float2 v = n2[(size_t)n * 64 + lane];
            float p = v.x * wa + v.y * wb;
            #pragma unroll
            for (int d = 1; d < 64; d <<= 1) p += __shfl_xor(p, d);
            if (lane == 0) {
                const bool m = mask32 ? (mi[n] != 0) : (mb[n] != 0);
                const float t = 1.f - 2.f / (__expf(2.f * p) + 1.f);
                outB[n] = m ? -1e9f : 10.f * t;
            }
        }
    }
}

extern "C" void kernel_launch(void* const* d_in, const int* in_sizes, int n_in,
                              void* d_out, int out_size, void* d_ws, size_t ws_size,
                              hipStream_t stream) {
    (void)n_in; (void)out_size;
    const float* node  = (const float*)d_in[0];
    const float* graph = (const float*)d_in[1];
    const float* ctx   = (const float*)d_in[2];
    const void*  mask  = d_in[3];
    const float* Wk1   = (const float*)d_in[4];
    const float* Wv    = (const float*)d_in[5];
    const float* Wk2   = (const float*)d_in[6];
    const float* Wqf   = (const float*)d_in[7];
    const float* Wout  = (const float*)d_in[8];
    const float* Wqs   = (const float*)d_in[9];

    const int B = in_sizes[1] / DD;
    const int N = in_sizes[0] / (B * DD);

    // workspace layout (bytes)
    const size_t wqf_bytes   = (size_t)B * 64 * 32 * 2;        // packed bf16 A-frags
    const size_t spart_bytes = (size_t)B * NS * NH * DD * 2;   // bf16
    const size_t mz_bytes    = (size_t)B * NS * NH * 2 * 4;
    const size_t w2_bytes    = (size_t)B * DD * 4;
    const size_t cnt_bytes   = (size_t)B * 4;
    const size_t need_bytes  = wqf_bytes + spart_bytes + mz_bytes + w2_bytes + cnt_bytes;

    if (N <= NMAX_PAD && ws_size >= need_bytes) {
        char* ws = (char*)d_ws;
        unsigned short* wq_frag  = (unsigned short*)ws;
        unsigned short* spart_ws = (unsigned short*)(ws + wqf_bytes);
        float*          mz_ws    = (float*)(ws + wqf_bytes + spart_bytes);
        float*          w2_ws    = (float*)(ws + wqf_bytes + spart_bytes + mz_bytes);
        int*            cnt      = (int*)(ws + wqf_bytes + spart_bytes + mz_bytes + w2_bytes);

        k0_prep<<<B, 128, 0, stream>>>(graph, ctx, Wk1, Wqf, Wqs, wq_frag, cnt);
        kA_mfma<<<dim3(NS / 2, B), 256, 0, stream>>>(node, wq_frag, mask, spart_ws, mz_ws,
                                                     w2_ws, Wv, Wout, Wk2, cnt, N);
        k5_logits<<<dim3(NS, B), 256, 0, stream>>>(node, w2_ws, mask, (float*)d_out, N);
    } else {
        decoder_fallback<<<B, TPB, 0, stream>>>(node, graph, ctx, mask,
                                                Wk1, Wv, Wk2, Wqf, Wout, Wqs,
                                                (float*)d_out, N);
    }
}

// Round 12
// 98.304 us; speedup vs baseline: 4.6322x; 4.6322x over previous
//
#include <hip/hip_runtime.h>
#include <hip/hip_bf16.h>
#include <stdint.h>

// DecoderCell, folded algebra + bf16-MFMA flash attention (v8 = r10 + tr-read PV).
//   k0: per b: q1 = graph@Wqf + ctx@Wqs; wq packed as bf16 MFMA A-frags
//   kA: per (b, PAIR of 64-row slices): stage -> bf16 LDS, scores^T via
//       mfma_16x16x32_bf16, softmax, P@node via MFMA with B-frags from
//       ds_read_b64_tr_b16 (as3-pointer addressing) -> bf16 partials + (m,z)
//   kB: per b: combine 16 slice partials -> s; mha -> q2 -> w2 (once per b)
//   k5: logits: mask ? -1e9 : 10*tanh(node[n,:].w2)   (streaming, 4096 blocks)

#define DD 128
#define NH 8
#define DHD 16
#define NS 16
#define TILE 64
#define RP 132
#define NMAX_PAD 1024

typedef short v8s __attribute__((ext_vector_type(8)));
typedef float v4f __attribute__((ext_vector_type(4)));
typedef unsigned int v2u __attribute__((ext_vector_type(2)));
typedef __attribute__((address_space(3))) const unsigned short lds_us;

__device__ __forceinline__ unsigned short f2bf(float x) {
    unsigned u = __float_as_uint(x);
    u += 0x7fffu + ((u >> 16) & 1u);   // RNE
    return (unsigned short)(u >> 16);
}
__device__ __forceinline__ float bf2f(unsigned short s) {
    return __uint_as_float((unsigned)s << 16);
}
__device__ __forceinline__ unsigned packbf2(float x, float y) {
    union { __hip_bfloat162 h; unsigned u; } cvt;
    cvt.h = __float22bfloat162_rn(make_float2(x, y));  // v_cvt_pk_bf16_f32
    return cvt.u;
}

// gfx950 LDS transpose-read. p is an address_space(3) pointer (32-bit LDS
// offset by construction — r7's bug was truncating a generic pointer).
// dest elem j = LDS element (off + j*16): rows r0..r0+3 at col c for
// p = &tA[ch][r0][c]  (16-element row stride matches HW).
__device__ __forceinline__ v2u ds_tr16(lds_us* p) {
    v2u r;
    asm volatile("ds_read_b64_tr_b16 %0, %1" : "=v"(r) : "v"(p));
    return r;
}
__device__ __forceinline__ v8s combine8(v2u lo, v2u hi) {
    union { struct { v2u lo, hi; } p; v8s v; } u;
    u.p.lo = lo; u.p.hi = hi;
    return u.v;
}

__device__ __forceinline__ bool detect_mask32(const void* maskp) {
    // int32 0/1 mask -> first 16 words all <=1; packed bool8 -> P ~ 3e-15
    const uint32_t* mw = (const uint32_t*)maskp;
    bool m32 = true;
    #pragma unroll
    for (int i = 0; i < 16; ++i) m32 = m32 && (mw[i] <= 1u);
    return m32;
}

// ---------------- k0: folded query -> packed bf16 A-fragments ----------------
__global__ __launch_bounds__(128)
void k0_prep(const float* __restrict__ graph, const float* __restrict__ ctx,
             const float* __restrict__ Wk1, const float* __restrict__ Wqf,
             const float* __restrict__ Wqs, unsigned short* __restrict__ wq_frag)
{
    __shared__ float q1[DD];
    __shared__ float wql[NH][DD];
    const int b = blockIdx.x, tid = threadIdx.x;
    const float* ge = graph + (size_t)b * DD;
    const float* sc = ctx + (size_t)b * (DD + 2);
    float acc = 0.f;
    #pragma unroll 4
    for (int k = 0; k < DD; ++k)     acc += ge[k] * Wqf[k * DD + tid];
    #pragma unroll 4
    for (int k = 0; k < DD + 2; ++k) acc += sc[k] * Wqs[k * DD + tid];
    q1[tid] = acc;
    __syncthreads();
    {
        const float* wrow = Wk1 + (size_t)tid * DD;   // row dp = tid
        #pragma unroll
        for (int h = 0; h < NH; ++h) {
            float a = 0.f;
            #pragma unroll
            for (int j = 0; j < DHD; ++j) a += wrow[h * DHD + j] * q1[h * DHD + j];
            wql[h][tid] = 0.25f * a;   // 1/sqrt(16)
        }
    }
    __syncthreads();
    // wq_frag[(b*64+l)*32 + kk*8 + i] = bf16(wql[c][kk*32+g*8+i]), c=l&15, g=l>>4
    for (int idx = tid; idx < 64 * 4; idx += 128) {
        const int l = idx >> 2, kk = idx & 3;
        const int c = l & 15, g = l >> 4;
        unsigned short v[8];
        if (c < NH) {
            #pragma unroll
            for (int i = 0; i < 8; ++i) v[i] = f2bf(wql[c][kk * 32 + g * 8 + i]);
        } else {
            #pragma unroll
            for (int i = 0; i < 8; ++i) v[i] = 0;
        }
        *(v8s*)&wq_frag[((size_t)b * 64 + l) * 32 + kk * 8] = *(v8s*)v;
    }
}

// ---------------- kA: MFMA flash over TWO <=64-row slices per block ----------------
// mfma_f32_16x16x32_bf16 lane layout (c=lane&15, g=lane>>4):
//   A[m][k]: m=c, k=g*8+i   B[k][n]: k=g*8+i, n=c   C[m][n]: m=g*4+r, n=c
__global__ __launch_bounds__(256)
void kA_mfma(const float* __restrict__ node, const unsigned short* __restrict__ wq_frag,
             const void* __restrict__ maskp, unsigned short* __restrict__ spart_ws,
             float* __restrict__ mz_ws, int N)
{
    __shared__ __align__(16) unsigned short tA[8][TILE][16]; // 16 KB node tile (bf16, col-subtiled)
    __shared__ __align__(16) unsigned short Ph[16][72];      // P^T [head][row]
    __shared__ float wmax[16][5];
    __shared__ float zpart[16][5];

    const int b = blockIdx.y, jj = blockIdx.x, tid = threadIdx.x;
    const int lane = tid & 63, w = tid >> 6;     // 4 waves
    const int c = lane & 15, g = lane >> 4;
    const int rows = (N + NS - 1) / NS;
    const int j0 = 2 * jj;

    const float* nodeB = node + (size_t)b * N * DD;
    const bool m32 = detect_mask32(maskp);
    const int32_t* mi = (const int32_t*)maskp + (size_t)b * N;
    const uint8_t* mb = (const uint8_t*)maskp + (size_t)b * N;

    // staging geometry: consecutive tids read consecutive 16B
    const int srow = tid >> 5;           // 0..7
    const int scol = (tid & 31) * 4;     // 0..124
    const int sch = scol >> 4, sc0 = scol & 15;

    auto load_slice = [&](int n0, int nend, float4* f) {
        const int nrows = nend - n0;
        #pragma unroll
        for (int i = 0; i < 8; ++i) {
            const int r = i * 8 + srow;
            f[i] = make_float4(0.f, 0.f, 0.f, 0.f);
            if (r < nrows)
                f[i] = *(const float4*)(nodeB + (size_t)(n0 + r) * DD + scol);
        }
    };
    auto store_slice = [&](const float4* f) {
        #pragma unroll
        for (int i = 0; i < 8; ++i) {
            const int r = i * 8 + srow;
            unsigned d[2];
            d[0] = packbf2(f[i].x, f[i].y);
            d[1] = packbf2(f[i].z, f[i].w);
            *(unsigned long long*)&tA[sch][r][sc0] = *(unsigned long long*)d;
        }
    };
    auto empty_slice = [&](int j) {
        unsigned short* sp = spart_ws + ((size_t)b * NS + j) * NH * DD;
        for (int o = tid; o < NH * DD; o += 256) sp[o] = 0;
        if (tid < NH) {
            float* mzp = mz_ws + (((size_t)b * NS + j) * NH + tid) * 2;
            mzp[0] = -1e30f; mzp[1] = 0.f;
        }
    };

    auto compute_slice = [&](int j, int n0, int nend, const v8s* aw) {
        // scores^T: wave w -> C[16 heads][rows w*16..w*16+15]
        const int nrow = n0 + w * 16 + c;
        v4f sc = {0.f, 0.f, 0.f, 0.f};
        #pragma unroll
        for (int kk = 0; kk < 4; ++kk) {
            const v8s bfrag = *(const v8s*)&tA[2 * kk + (g >> 1)][w * 16 + c][(g & 1) * 8];
            sc = __builtin_amdgcn_mfma_f32_16x16x32_bf16(aw[kk], bfrag, sc, 0, 0, 0);
        }
        float s4[4];
        {
            const bool valid = nrow < nend;
            const bool msk = valid && (m32 ? (mi[nrow] != 0) : (mb[nrow] != 0));
            #pragma unroll
            for (int r = 0; r < 4; ++r)
                s4[r] = !valid ? -1e30f : (msk ? -1e9f : sc[r]);
        }
        // per-wave max over 16 rows (xor<16 stays within g-group)
        {
            float mx[4];
            #pragma unroll
            for (int r = 0; r < 4; ++r) mx[r] = s4[r];
            #pragma unroll
            for (int d = 1; d < 16; d <<= 1) {
                #pragma unroll
                for (int r = 0; r < 4; ++r) mx[r] = fmaxf(mx[r], __shfl_xor(mx[r], d));
            }
            if (c == 0) {
                #pragma unroll
                for (int r = 0; r < 4; ++r) wmax[g * 4 + r][w] = mx[r];
            }
        }
        __syncthreads();
        // e, z, P^T
        {
            float e4[4];
            #pragma unroll
            for (int r = 0; r < 4; ++r) {
                const int h = g * 4 + r;
                const float m = fmaxf(fmaxf(wmax[h][0], wmax[h][1]),
                                      fmaxf(wmax[h][2], wmax[h][3]));
                e4[r] = __expf(s4[r] - m);
            }
            float zr[4];
            #pragma unroll
            for (int r = 0; r < 4; ++r) zr[r] = e4[r];
            #pragma unroll
            for (int d = 1; d < 16; d <<= 1) {
                #pragma unroll
                for (int r = 0; r < 4; ++r) zr[r] += __shfl_xor(zr[r], d);
            }
            if (c == 0) {
                #pragma unroll
                for (int r = 0; r < 4; ++r) zpart[g * 4 + r][w] = zr[r];
            }
            #pragma unroll
            for (int r = 0; r < 4; ++r)
                Ph[g * 4 + r][w * 16 + c] = f2bf(e4[r]);
        }
        __syncthreads();
        // ---- P @ node: B-frags via ds_read_b64_tr_b16 (canonical k-order:
        // dest j of &tA[ch][r0][c] = tA[ch][r0+j][c]) — bit-identical to the
        // verified scalar-gather path when the base is a true LDS offset.
        v2u tr[8];
        #pragma unroll
        for (int sl = 0; sl < 2; ++sl) {
            #pragma unroll
            for (int chk = 0; chk < 2; ++chk) {
                #pragma unroll
                for (int hf = 0; hf < 2; ++hf) {
                    lds_us* p = (lds_us*)&tA[2 * w + chk][sl * 32 + g * 8 + hf * 4][c];
                    tr[sl * 4 + chk * 2 + hf] = ds_tr16(p);
                }
            }
        }
        asm volatile("s_waitcnt lgkmcnt(0)" ::: "memory");
        __builtin_amdgcn_sched_barrier(0);

        v4f c0v = {0.f, 0.f, 0.f, 0.f}, c1v = {0.f, 0.f, 0.f, 0.f};
        #pragma unroll
        for (int sl = 0; sl < 2; ++sl) {
            const v8s pa  = *(const v8s*)&Ph[c][sl * 32 + g * 8];
            const v8s bb0 = combine8(tr[sl * 4 + 0], tr[sl * 4 + 1]);
            const v8s bb1 = combine8(tr[sl * 4 + 2], tr[sl * 4 + 3]);
            c0v = __builtin_amdgcn_mfma_f32_16x16x32_bf16(pa, bb0, c0v, 0, 0, 0);
            c1v = __builtin_amdgcn_mfma_f32_16x16x32_bf16(pa, bb1, c1v, 0, 0, 0);
        }
        // outputs (heads 0..7 live in m = g*4+r < 8)
        if (g < 2) {
            unsigned short* sp = spart_ws + ((size_t)b * NS + j) * NH * DD;
            #pragma unroll
            for (int r = 0; r < 4; ++r) {
                sp[(g * 4 + r) * DD + (2 * w)     * 16 + c] = f2bf(c0v[r]);
                sp[(g * 4 + r) * DD + (2 * w + 1) * 16 + c] = f2bf(c1v[r]);
            }
        }
        if (tid < NH) {
            const float z = zpart[tid][0] + zpart[tid][1] + zpart[tid][2] + zpart[tid][3];
            const float m = fmaxf(fmaxf(wmax[tid][0], wmax[tid][1]),
                                  fmaxf(wmax[tid][2], wmax[tid][3]));
            float* mzp = mz_ws + (((size_t)b * NS + j) * NH + tid) * 2;
            mzp[0] = m;
            mzp[1] = z;
        }
    };

    const int n0_a = j0 * rows,       nend_a = min(n0_a + rows, N);
    const int n0_b = (j0 + 1) * rows, nend_b = min(n0_b + rows, N);
    const bool have_a = n0_a < nend_a;
    const bool have_b = n0_b < nend_b;

    if (!have_a) {   // both empty (N tiny)
        empty_slice(j0);
        __syncthreads();
        if (j0 + 1 < NS) empty_slice(j0 + 1);
        return;
    }

    // ---- wq A-fragments: 4 x coalesced global b128 (pre-packed by k0)
    v8s aw[4];
    {
        const unsigned short* wf = wq_frag + ((size_t)b * 64 + lane) * 32;
        #pragma unroll
        for (int kk = 0; kk < 4; ++kk)
            aw[kk] = *(const v8s*)&wf[kk * 8];
    }

    float4 fr[8];
    load_slice(n0_a, nend_a, fr);
    store_slice(fr);

    float4 fr2[8];
    if (have_b) load_slice(n0_b, nend_b, fr2);   // issue early; lands during compute A

    __syncthreads();              // tile A ready
    compute_slice(j0, n0_a, nend_a, aw);
    __syncthreads();              // all PV reads of tA done

    if (have_b) {
        store_slice(fr2);
        __syncthreads();          // tile B ready
        compute_slice(j0 + 1, n0_b, nend_b, aw);
    } else if (j0 + 1 < NS) {
        empty_slice(j0 + 1);
    }
}

// ---------------- kB: combine partials + mha + q2 + w2 (once per b) ----------------
__global__ __launch_bounds__(128)
void kB_combine(const unsigned short* __restrict__ spart_ws, const float* __restrict__ mz_ws,
                const float* __restrict__ Wv, const float* __restrict__ Wout,
                const float* __restrict__ Wk2, float* __restrict__ w2_ws)
{
    __shared__ float m_l[NH * NS], z_l[NH * NS], wt[NH * NS];
    __shared__ float s_l[NH * DD];
    __shared__ float mha_l[DD];
    __shared__ float q2_l[DD];
    const int b = blockIdx.x, tid = threadIdx.x;

    {   // 128 threads == NH*NS entries
        const int h = tid >> 4, j = tid & 15;
        const float* mzp = mz_ws + (((size_t)b * NS + j) * NH + h) * 2;
        m_l[h * NS + j] = mzp[0];
        z_l[h * NS + j] = mzp[1];
    }
    __syncthreads();
    if (tid < NH) {
        const int h = tid;
        float M = -1e30f;
        #pragma unroll
        for (int j = 0; j < NS; ++j) M = fmaxf(M, m_l[h * NS + j]);
        float Z = 0.f;
        float wv[NS];
        #pragma unroll
        for (int j = 0; j < NS; ++j) {
            wv[j] = __expf(m_l[h * NS + j] - M);
            Z += z_l[h * NS + j] * wv[j];
        }
        const float rz = 1.f / Z;
        #pragma unroll
        for (int j = 0; j < NS; ++j) wt[h * NS + j] = wv[j] * rz;
    }
    __syncthreads();
    const unsigned short* sp = spart_ws + (size_t)b * NS * NH * DD;
    for (int o = tid; o < NH * DD; o += 128) {
        const int h = o >> 7;
        float s = 0.f;
        #pragma unroll
        for (int j = 0; j < NS; ++j)
            s += bf2f(sp[(size_t)j * NH * DD + o]) * wt[h * NS + j];
        s_l[o] = s;
    }
    __syncthreads();
    {   // mha[e] = s[h(e)] . Wv[:,e]
        const int h = tid >> 4;
        float a = 0.f;
        for (int dp = 0; dp < DD; ++dp) a += s_l[h * DD + dp] * Wv[dp * DD + tid];
        mha_l[tid] = a;
    }
    __syncthreads();
    {   // q2 = mha @ Wout
        float a = 0.f;
        for (int e = 0; e < DD; ++e) a += mha_l[e] * Wout[e * DD + tid];
        q2_l[tid] = a;
    }
    __syncthreads();
    {   // w2 = (Wk2 @ q2) / sqrt(128)
        const float4* row = (const float4*)(Wk2 + (size_t)tid * DD);
        float a = 0.f;
        #pragma unroll
        for (int k = 0; k < 32; ++k) {
            const float4 w = row[k];
            a += w.x * q2_l[4*k] + w.y * q2_l[4*k+1] + w.z * q2_l[4*k+2] + w.w * q2_l[4*k+3];
        }
        w2_ws[(size_t)b * DD + tid] = a * 0.08838834764831845f;  // 1/sqrt(128)
    }
}

// ---------------- k5: logits ----------------
__global__ __launch_bounds__(256)
void k5_logits(const float* __restrict__ node, const float* __restrict__ w2_ws,
               const void* __restrict__ maskp, float* __restrict__ out, int N)
{
    const int b = blockIdx.y, j = blockIdx.x, tid = threadIdx.x;
    const int rows = (N + NS - 1) / NS;
    const int n0 = j * rows;
    const int nend = min(n0 + rows, N);
    const bool m32 = detect_mask32(maskp);
    const int32_t* mi = (const int32_t*)maskp + (size_t)b * N;
    const uint8_t* mb = (const uint8_t*)maskp + (size_t)b * N;
    const int sub = tid & 7, rr = tid >> 3;

    const float4* wv = (const float4*)(w2_ws + (size_t)b * DD + sub * 16);
    const float4 w0 = wv[0], w1 = wv[1], w2v = wv[2], w3 = wv[3];
    const float* nodeB = node + (size_t)b * N * DD;
    float* outB = out + (size_t)b * N;

    for (int n = n0 + rr; n < nend; n += 32) {
        const float4* nr = (const float4*)(nodeB + (size_t)n * DD + sub * 16);
        const float4 a0 = nr[0], a1 = nr[1], a2 = nr[2], a3 = nr[3];
        float p = a0.x*w0.x + a0.y*w0.y + a0.z*w0.z + a0.w*w0.w
                + a1.x*w1.x + a1.y*w1.y + a1.z*w1.z + a1.w*w1.w
                + a2.x*w2v.x + a2.y*w2v.y + a2.z*w2v.z + a2.w*w2v.w
                + a3.x*w3.x + a3.y*w3.y + a3.z*w3.z + a3.w*w3.w;
        p += __shfl_xor(p, 1);
        p += __shfl_xor(p, 2);
        p += __shfl_xor(p, 4);
        if (sub == 0) {
            const bool m = m32 ? (mi[n] != 0) : (mb[n] != 0);
            const float t = 1.f - 2.f / (__expf(2.f * p) + 1.f);  // tanh
            outB[n] = m ? -1e9f : 10.f * t;
        }
    }
}

// ================ fallback: round-1 monolithic kernel ================
#define TPB 512
#define NMAX 1000
#define SPAD 9

__global__ __launch_bounds__(TPB)
void decoder_fallback(const float* __restrict__ node, const float* __restrict__ graph,
                      const float* __restrict__ ctx, const void* __restrict__ maskp,
                      const float* __restrict__ Wk1, const float* __restrict__ Wv,
                      const float* __restrict__ Wk2, const float* __restrict__ Wqf,
                      const float* __restrict__ Wout, const float* __restrict__ Wqs,
                      float* __restrict__ out, int N)
{
    __shared__ float node_tile[TILE * RP];
    __shared__ float scores[NMAX * SPAD];
    __shared__ float wq[NH * RP];
    __shared__ float s_lds[NH * RP];
    __shared__ float q1[DD];
    __shared__ float mha[DD];
    __shared__ float q2[DD];
    __shared__ float w2[DD];

    const int b = blockIdx.x, tid = threadIdx.x, lane = tid & 63, wave = tid >> 6;
    const bool mask32 = detect_mask32(maskp);
    const int32_t* mi = (const int32_t*)maskp + (size_t)b * N;
    const uint8_t* mb = (const uint8_t*)maskp + (size_t)b * N;
    const float* nodeB = node + (size_t)b * N * DD;

    if (tid < DD) {
        const float* ge = graph + (size_t)b * DD;
        const float* sc = ctx + (size_t)b * (DD + 2);
        float acc = 0.f;
        for (int k = 0; k < DD; ++k)     acc += ge[k] * Wqf[k * DD + tid];
        for (int k = 0; k < DD + 2; ++k) acc += sc[k] * Wqs[k * DD + tid];
        q1[tid] = acc;
    }
    __syncthreads();
    for (int idx = tid; idx < NH * DD; idx += TPB) {
        const int h = idx >> 7, dp = idx & (DD - 1);
        const float* wrow = Wk1 + dp * DD + h * DHD;
        float acc = 0.f;
        #pragma unroll
        for (int j = 0; j < DHD; ++j) acc += wrow[j] * q1[h * DHD + j];
        wq[h * RP + dp] = 0.25f * acc;
    }
    __syncthreads();
    const int ntiles = (N + TILE - 1) / TILE;
    const int n_local = tid >> 3, hA = tid & 7;
    for (int t = 0; t < ntiles; ++t) {
        const int n0 = t * TILE;
        #pragma unroll
        for (int cc = 0; cc < 4; ++cc) {
            const int idx = cc * (TPB * 4) + tid * 4;
            const int row = idx >> 7, col = idx & (DD - 1);
            if (n0 + row < N)
                *(float4*)&node_tile[row * RP + col] =
                    *(const float4*)(nodeB + (size_t)(n0 + row) * DD + col);
        }
        __syncthreads();
        if (n0 + n_local < N) {
            const float4* nr = (const float4*)&node_tile[n_local * RP];
            const float4* wr = (const float4*)&wq[hA * RP];
            float acc = 0.f;
            #pragma unroll
            for (int k = 0; k < DD / 4; ++k) {
                const float4 a = nr[k], wv = wr[k];
                acc += a.x * wv.x + a.y * wv.y + a.z * wv.z + a.w * wv.w;
            }
            scores[(n0 + n_local) * SPAD + hA] = acc;
        }
        __syncthreads();
    }
    {
        const int h = wave;
        float sm[16];
        #pragma unroll
        for (int k = 0; k < 16; ++k) {
            const int n = lane + 64 * k;
            float v = -1e9f;
            if (n < N) {
                const bool m = mask32 ? (mi[n] != 0) : (mb[n] != 0);
                v = m ? -1e9f : scores[n * SPAD + h];
            }
            sm[k] = v;
        }
        float mx = sm[0];
        #pragma unroll
        for (int k = 1; k < 16; ++k) mx = fmaxf(mx, sm[k]);
        #pragma unroll
        for (int d = 1; d < 64; d <<= 1) mx = fmaxf(mx, __shfl_xor(mx, d));
        float e[16];
        float sum = 0.f;
        #pragma unroll
        for (int k = 0; k < 16; ++k) {
            const int n = lane + 64 * k;
            e[k] = (n < N) ? __expf(sm[k] - mx) : 0.f;
            sum += e[k];
        }
        #pragma unroll
        for (int d = 1; d < 64; d <<= 1) sum += __shfl_xor(sum, d);
        const float rinv = 1.f / sum;
        #pragma unroll
        for (int k = 0; k < 16; ++k) {
            const int n = lane + 64 * k;
            if (n < N) scores[n * SPAD + h] = e[k] * rinv;
        }
    }
    __syncthreads();
    {
        const int h = wave;
        const float2* n2 = (const float2*)nodeB;
        float a0 = 0.f, a1 = 0.f;
        #pragma unroll 4
        for (int n = 0; n < N; ++n) {
            const float at = scores[n * SPAD + h];
            const float2 v = n2[(size_t)n * 64 + lane];
            a0 += at * v.x;
            a1 += at * v.y;
        }
        s_lds[h * RP + 2 * lane] = a0;
        s_lds[h * RP + 2 * lane + 1] = a1;
    }
    __syncthreads();
    if (tid < DD) {
        const int h = tid >> 4;
        float acc = 0.f;
        for (int dp = 0; dp < DD; ++dp) acc += s_lds[h * RP + dp] * Wv[dp * DD + tid];
        mha[tid] = acc;
    }
    __syncthreads();
    if (tid < DD) {
        float acc = 0.f;
        for (int e = 0; e < DD; ++e) acc += mha[e] * Wout[e * DD + tid];
        q2[tid] = acc;
    }
    __syncthreads();
    if (tid < DD) {
        const float4* row = (const float4*)(Wk2 + tid * DD);
        float acc = 0.f;
        #pragma unroll
        for (int k = 0; k < DD / 4; ++k) {
            const float4 wv = row[k];
            acc += wv.x * q2[4*k] + wv.y * q2[4*k+1] + wv.z * q2[4*k+2] + wv.w * q2[4*k+3];
        }
        w2[tid] = acc * 0.08838834764831845f;
    }
    __syncthreads();
    {
        const float wa = w2[2 * lane], wb = w2[2 * lane + 1];
        const float2* n2 = (const float2*)nodeB;
        float* outB = out + (size_t)b * N;
        for (int n = wave; n < N; n += NH) {
            const float2 v = n2[(size_t)n * 64 + lane];
            float p = v.x * wa + v.y * wb;
            #pragma unroll
            for (int d = 1; d < 64; d <<= 1) p += __shfl_xor(p, d);
            if (lane == 0) {
                const bool m = mask32 ? (mi[n] != 0) : (mb[n] != 0);
                const float t = 1.f - 2.f / (__expf(2.f * p) + 1.f);
                outB[n] = m ? -1e9f : 10.f * t;
            }
        }
    }
}

extern "C" void kernel_launch(void* const* d_in, const int* in_sizes, int n_in,
                              void* d_out, int out_size, void* d_ws, size_t ws_size,
                              hipStream_t stream) {
    (void)n_in; (void)out_size;
    const float* node  = (const float*)d_in[0];
    const float* graph = (const float*)d_in[1];
    const float* ctx   = (const float*)d_in[2];
    const void*  mask  = d_in[3];
    const float* Wk1   = (const float*)d_in[4];
    const float* Wv    = (const float*)d_in[5];
    const float* Wk2   = (const float*)d_in[6];
    const float* Wqf   = (const float*)d_in[7];
    const float* Wout  = (const float*)d_in[8];
    const float* Wqs   = (const float*)d_in[9];

    const int B = in_sizes[1] / DD;
    const int N = in_sizes[0] / (B * DD);

    // workspace layout (bytes)
    const size_t wqf_bytes   = (size_t)B * 64 * 32 * 2;        // packed bf16 A-frags
    const size_t spart_bytes = (size_t)B * NS * NH * DD * 2;   // bf16
    const size_t mz_bytes    = (size_t)B * NS * NH * 2 * 4;
    const size_t w2_bytes    = (size_t)B * DD * 4;
    const size_t need_bytes  = wqf_bytes + spart_bytes + mz_bytes + w2_bytes;

    if (N <= NMAX_PAD && ws_size >= need_bytes) {
        char* ws = (char*)d_ws;
        unsigned short* wq_frag  = (unsigned short*)ws;
        unsigned short* spart_ws = (unsigned short*)(ws + wqf_bytes);
        float*          mz_ws    = (float*)(ws + wqf_bytes + spart_bytes);
        float*          w2_ws    = (float*)(ws + wqf_bytes + spart_bytes + mz_bytes);

        k0_prep<<<B, 128, 0, stream>>>(graph, ctx, Wk1, Wqf, Wqs, wq_frag);
        kA_mfma<<<dim3(NS / 2, B), 256, 0, stream>>>(node, wq_frag, mask, spart_ws, mz_ws, N);
        kB_combine<<<B, 128, 0, stream>>>(spart_ws, mz_ws, Wv, Wout, Wk2, w2_ws);
        k5_logits<<<dim3(NS, B), 256, 0, stream>>>(node, w2_ws, mask, (float*)d_out, N);
    } else {
        decoder_fallback<<<B, TPB, 0, stream>>>(node, graph, ctx, mask,
                                                Wk1, Wv, Wk2, Wqf, Wout, Wqs,
                                                (float*)d_out, N);
    }
}